// Round 1
// baseline (200.199 us; speedup 1.0000x reference)
//
#include <hip/hip_runtime.h>

// GCN forward on MI355X:
//   out = log_softmax(adj @ (relu(adj @ (x@W1) + b1) @ W2) + b2)
// N=8192, NFEAT=512, NHID=128, NCLASS=40. adj is 256MB f32, read twice (dependency).
// Strategy: bf16 MFMA (16x16x32) with on-the-fly f32->bf16 conversion of adj;
// intermediates stored bf16 in B^T layout so B-fragments are contiguous 16B loads.

using bf16x8 = __attribute__((ext_vector_type(8))) __bf16;
using f32x4  = __attribute__((ext_vector_type(4))) float;
using u16x4  = __attribute__((ext_vector_type(4))) unsigned short;

#define NROW 8192
#define KFEAT 512
#define HID 128
#define NCLS 40

// f32 -> bf16 round-to-nearest-even, bit trick (no lib dependency)
__device__ __forceinline__ unsigned short f2b(float f) {
  union { float f; unsigned u; } v; v.f = f;
  unsigned r = v.u + 0x7fffu + ((v.u >> 16) & 1u);
  return (unsigned short)(r >> 16);
}

__device__ __forceinline__ bf16x8 ldb8(const unsigned short* p) {
  return *reinterpret_cast<const bf16x8*>(p);
}

// Core K-loop: BM=32 rows/block, 512 threads (8 waves), BK=64, double-buffered
// swizzled LDS for A (f32 global -> bf16), B read direct global->reg (bf16 B^T
// layout, rows contiguous in K). Wave (wr=wave/WC, wc=wave%WC) computes MR
// 16x16 fragments at rows wm0+m*16, cols wc*16. One barrier per K-tile:
// iter t computes from buf[t&1], writes buf[(t+1)&1] (disjoint), barrier at top
// makes writes visible. A-loads + B-loads for t+1 issued at top of t (latency
// hidden under MFMA of tile t).
template<int LDA_, int LDB_, int NT, int WC, int MR>
__device__ __forceinline__ void gemm_core(const float* __restrict__ Ab,
                                          const unsigned short* __restrict__ Bt,
                                          unsigned short (&As)[2][2048],
                                          f32x4 (&acc)[MR],
                                          int tid)
{
  const int lane = tid & 63;
  const int wave = tid >> 6;
  const int wr = wave / WC;
  const int wc = wave % WC;
  const int wm0 = wr * MR * 16;
  const int wn0 = wc * 16;
  const int l15 = lane & 15;
  const int lg  = lane >> 4;

  // staging: thread covers 4 f32 of the 32x64 A tile
  const int srow = tid >> 4;          // 0..31
  const int sc4  = (tid & 15) * 4;    // 0..60
  const float* ap = Ab + (size_t)srow * LDA_ + sc4;
  const unsigned short* bp = Bt + (size_t)(wn0 + l15) * LDB_ + lg * 8;

  f32x4 areg;
  bf16x8 bcur0, bcur1, bnxt0, bnxt1;

  // prologue: stage tile 0
  areg = *reinterpret_cast<const f32x4*>(ap);
  {
    u16x4 p;
    p[0]=f2b(areg[0]); p[1]=f2b(areg[1]); p[2]=f2b(areg[2]); p[3]=f2b(areg[3]);
    int off = (srow * 64 + sc4) ^ ((srow & 7) << 3);  // XOR swizzle (16B chunks)
    *reinterpret_cast<u16x4*>(&As[0][off]) = p;
  }
  bcur0 = ldb8(bp);
  bcur1 = ldb8(bp + 32);

  int cur = 0;
  for (int kt = 0; kt < NT; ++kt) {
    __syncthreads();  // buf[cur] (written end of prev iter / prologue) visible
    const bool more = (kt + 1 < NT);
    if (more) {
      areg  = *reinterpret_cast<const f32x4*>(ap + (kt + 1) * 64);
      bnxt0 = ldb8(bp + (size_t)(kt + 1) * 64);
      bnxt1 = ldb8(bp + (size_t)(kt + 1) * 64 + 32);
    }
#pragma unroll
    for (int kk = 0; kk < 2; ++kk) {
      bf16x8 bf = kk ? bcur1 : bcur0;
#pragma unroll
      for (int m = 0; m < MR; ++m) {
        int row = wm0 + m * 16 + l15;
        int off = (row * 64 + kk * 32 + lg * 8) ^ ((row & 7) << 3);
        bf16x8 af = *reinterpret_cast<const bf16x8*>(&As[cur][off]);
        acc[m] = __builtin_amdgcn_mfma_f32_16x16x32_bf16(af, bf, acc[m], 0, 0, 0);
      }
    }
    if (more) {
      u16x4 p;
      p[0]=f2b(areg[0]); p[1]=f2b(areg[1]); p[2]=f2b(areg[2]); p[3]=f2b(areg[3]);
      int off = (srow * 64 + sc4) ^ ((srow & 7) << 3);
      *reinterpret_cast<u16x4*>(&As[cur ^ 1][off]) = p;
      bcur0 = bnxt0; bcur1 = bnxt1;
    }
    cur ^= 1;
  }
}

// K0: W1t[n][k] = bf16(W1[k][n]), [128][512]
__global__ __launch_bounds__(256) void k0_w1t(const float* __restrict__ W1,
                                              unsigned short* __restrict__ W1t)
{
  int id = blockIdx.x * 256 + threadIdx.x;   // 65536 total
  int k = id >> 7, n = id & 127;
  W1t[n * KFEAT + k] = f2b(W1[k * HID + n]);
}

// K1: support_t[c][m] = (x @ W1)[m][c], bf16 [128][8192]
__global__ __launch_bounds__(512) void k1_support(const float* __restrict__ X,
                                                  const unsigned short* __restrict__ W1t,
                                                  unsigned short* __restrict__ St)
{
  __shared__ unsigned short As[2][2048];
  const int tid = threadIdx.x;
  const int m0 = blockIdx.x * 32;
  f32x4 acc[2] = {};
  gemm_core<KFEAT, KFEAT, KFEAT / 64, 8, 2>(X + (size_t)m0 * KFEAT, W1t, As, acc, tid);
  const int lane = tid & 63, wave = tid >> 6;
  const int l15 = lane & 15, lg = lane >> 4;
  const int col = wave * 16 + l15;
#pragma unroll
  for (int m = 0; m < 2; ++m)
#pragma unroll
    for (int i = 0; i < 4; ++i) {
      int mm = m0 + m * 16 + lg * 4 + i;
      St[(size_t)col * NROW + mm] = f2b(acc[m][i]);
    }
}

// K2: h[m][c] = relu((adj @ support)[m][c] + b1[c]), bf16 [8192][128]
__global__ __launch_bounds__(512) void k2_hidden(const float* __restrict__ ADJ,
                                                 const unsigned short* __restrict__ St,
                                                 const float* __restrict__ b1,
                                                 unsigned short* __restrict__ H)
{
  __shared__ unsigned short As[2][2048];
  const int tid = threadIdx.x;
  const int m0 = blockIdx.x * 32;
  f32x4 acc[2] = {};
  gemm_core<NROW, NROW, NROW / 64, 8, 2>(ADJ + (size_t)m0 * NROW, St, As, acc, tid);
  const int lane = tid & 63, wave = tid >> 6;
  const int l15 = lane & 15, lg = lane >> 4;
  const int col = wave * 16 + l15;
  const float bias = b1[col];
#pragma unroll
  for (int m = 0; m < 2; ++m)
#pragma unroll
    for (int i = 0; i < 4; ++i) {
      int mm = m0 + m * 16 + lg * 4 + i;
      float v = acc[m][i] + bias;
      v = v > 0.f ? v : 0.f;
      H[(size_t)mm * HID + col] = f2b(v);
    }
}

// K3: s2_t[c][m] = (h @ W2)[m][c], bf16 [64][8192], cols 40..63 are zero pad
__global__ __launch_bounds__(256) void k3_s2(const unsigned short* __restrict__ H,
                                             const float* __restrict__ W2,
                                             unsigned short* __restrict__ S2t)
{
  __shared__ unsigned short W2t[64 * 136];  // [col][k], row stride 136 (conflict-safe)
  const int tid = threadIdx.x;
  {
    const int n = tid >> 2;
    const int ks = (tid & 3) * 32;
    for (int j = 0; j < 32; ++j) {
      int k = ks + j;
      float v = (n < NCLS) ? W2[k * NCLS + n] : 0.f;
      W2t[n * 136 + k] = f2b(v);
    }
  }
  __syncthreads();
  const int lane = tid & 63, wave = tid >> 6;
  const int l15 = lane & 15, lg = lane >> 4;
  const int m0 = blockIdx.x * 64;
  const int rowm = m0 + wave * 16 + l15;
  f32x4 acc[4] = {};
#pragma unroll
  for (int kk = 0; kk < 4; ++kk) {
    bf16x8 af = *reinterpret_cast<const bf16x8*>(H + (size_t)rowm * HID + kk * 32 + lg * 8);
#pragma unroll
    for (int n = 0; n < 4; ++n) {
      bf16x8 bf = *reinterpret_cast<const bf16x8*>(&W2t[(n * 16 + l15) * 136 + kk * 32 + lg * 8]);
      acc[n] = __builtin_amdgcn_mfma_f32_16x16x32_bf16(af, bf, acc[n], 0, 0, 0);
    }
  }
#pragma unroll
  for (int n = 0; n < 4; ++n)
#pragma unroll
    for (int i = 0; i < 4; ++i) {
      int col = n * 16 + l15;
      int mm = m0 + wave * 16 + lg * 4 + i;
      S2t[(size_t)col * NROW + mm] = f2b(acc[n][i]);
    }
}

// K4: logits = adj @ s2 + b2; out = log_softmax(logits) row-wise, f32 [8192][40]
__global__ __launch_bounds__(512) void k4_out(const float* __restrict__ ADJ,
                                              const unsigned short* __restrict__ S2t,
                                              const float* __restrict__ b2,
                                              float* __restrict__ OUT)
{
  __shared__ unsigned short As[2][2048];
  __shared__ float Ll[32 * 65];
  const int tid = threadIdx.x;
  const int m0 = blockIdx.x * 32;
  f32x4 acc[1] = {};
  gemm_core<NROW, NROW, NROW / 64, 4, 1>(ADJ + (size_t)m0 * NROW, S2t, As, acc, tid);
  const int lane = tid & 63, wave = tid >> 6;
  const int l15 = lane & 15, lg = lane >> 4;
  const int wc = wave & 3, wr = wave >> 2;
  const int col = wc * 16 + l15;
  if (col < NCLS) {
    const float bias = b2[col];
#pragma unroll
    for (int i = 0; i < 4; ++i) {
      int row = wr * 16 + lg * 4 + i;
      Ll[row * 65 + col] = acc[0][i] + bias;
    }
  }
  __syncthreads();
  // log_softmax over 40 classes: 16 threads per row
  const int row = tid >> 4;   // 0..31
  const int sub = tid & 15;
  float vals[3];
  int nc = 0;
  float mx = -3.4e38f;
  for (int c = sub; c < NCLS; c += 16) {
    float v = Ll[row * 65 + c];
    vals[nc++] = v;
    mx = fmaxf(mx, v);
  }
#pragma unroll
  for (int d = 1; d < 16; d <<= 1) mx = fmaxf(mx, __shfl_xor(mx, d));
  float se = 0.f;
  for (int j = 0; j < nc; ++j) se += expf(vals[j] - mx);
#pragma unroll
  for (int d = 1; d < 16; d <<= 1) se += __shfl_xor(se, d);
  const float lse = mx + logf(se);
  int j = 0;
  for (int c = sub; c < NCLS; c += 16) {
    OUT[(size_t)(m0 + row) * NCLS + c] = vals[j++] - lse;
  }
}

extern "C" void kernel_launch(void* const* d_in, const int* in_sizes, int n_in,
                              void* d_out, int out_size, void* d_ws, size_t ws_size,
                              hipStream_t stream)
{
  const float* x   = (const float*)d_in[0];
  const float* adj = (const float*)d_in[1];
  const float* W1  = (const float*)d_in[2];
  const float* b1  = (const float*)d_in[3];
  const float* W2  = (const float*)d_in[4];
  const float* b2  = (const float*)d_in[5];
  float* out = (float*)d_out;

  char* ws = (char*)d_ws;
  unsigned short* W1t = (unsigned short*)(ws);                          // 128KB
  unsigned short* St  = (unsigned short*)(ws + 131072);                 // 2MB
  unsigned short* H   = (unsigned short*)(ws + 131072 + 2097152);       // 2MB
  unsigned short* S2t = (unsigned short*)(ws + 131072 + 2 * 2097152);   // 1MB

  hipLaunchKernelGGL(k0_w1t,    dim3(256), dim3(256), 0, stream, W1, W1t);
  hipLaunchKernelGGL(k1_support,dim3(256), dim3(512), 0, stream, x, W1t, St);
  hipLaunchKernelGGL(k2_hidden, dim3(256), dim3(512), 0, stream, adj, St, b1, H);
  hipLaunchKernelGGL(k3_s2,     dim3(128), dim3(256), 0, stream, H, W2, S2t);
  hipLaunchKernelGGL(k4_out,    dim3(256), dim3(512), 0, stream, adj, S2t, b2, out);
}